// Round 11
// baseline (76.207 us; speedup 1.0000x reference)
//
#include <hip/hip_runtime.h>

#define NNODES 2048
#define NHEAD 8
#define DKDIM 64

typedef unsigned int uint;
typedef unsigned short ushort;
typedef unsigned char uchar;
typedef __fp16 h2 __attribute__((ext_vector_type(2)));
typedef __fp16 h8 __attribute__((ext_vector_type(8)));
typedef float f4 __attribute__((ext_vector_type(4)));

#define KSCALE 0.18033688011112042f   // 0.125 * log2(e)
#define CLAMP2 14.426950408889634f    // 10 * log2(e)

__device__ __forceinline__ uint pk2(float a, float b) {
    union { h2 h; uint u; } x; x.h = __builtin_amdgcn_cvt_pkrtz(a, b); return x.u;
}

// ---- k -> fp16 [head][node][dim] (pre-scaled), linear; also zeroes A ----
__global__ void conv_k(const float* __restrict__ k, uint4* __restrict__ kc,
                       uint4* __restrict__ A4) {
    int i = blockIdx.x * 256 + threadIdx.x;      // 0..131071
    int dim8 = i & 7, node = (i >> 3) & 2047, h = i >> 14;
    const float* src = k + (size_t)node * 512 + h * 64 + dim8 * 8;
    float4 f0 = *(const float4*)src;
    float4 f1 = *(const float4*)(src + 4);
    uint4 o;
    o.x = pk2(f0.x * KSCALE, f0.y * KSCALE);
    o.y = pk2(f0.z * KSCALE, f0.w * KSCALE);
    o.z = pk2(f1.x * KSCALE, f1.y * KSCALE);
    o.w = pk2(f1.z * KSCALE, f1.w * KSCALE);
    kc[(h * 2048 + node) * 8 + dim8] = o;
    uint4 zz = {0u, 0u, 0u, 0u};
    A4[i] = zz;
    A4[i + 131072] = zz;
}

// ---- v -> fp16 transposed [head][dim][node], linear ----
__global__ void conv_vT(const float* __restrict__ v, ushort* __restrict__ vt) {
    __shared__ float tile[64][65];
    int b = blockIdx.x;        // 256 = 8 heads * 32 node-tiles
    int h = b & 7, tn = b >> 3;
    int t = threadIdx.x;
    int nl = t >> 2, dq = (t & 3) * 16;
    const float* src = v + ((size_t)(tn * 64 + nl)) * 512 + h * 64 + dq;
#pragma unroll
    for (int i = 0; i < 4; ++i) {
        float4 f = *(const float4*)(src + i * 4);
        tile[nl][dq + i * 4 + 0] = f.x;
        tile[nl][dq + i * 4 + 1] = f.y;
        tile[nl][dq + i * 4 + 2] = f.z;
        tile[nl][dq + i * 4 + 3] = f.w;
    }
    __syncthreads();
    int dim = t >> 2, nq = (t & 3) * 16;
    uint wv[8];
#pragma unroll
    for (int i = 0; i < 8; ++i)
        wv[i] = pk2(tile[nq + 2 * i][dim], tile[nq + 2 * i + 1][dim]);
    char* base = (char*)vt + ((size_t)(h * 64 + dim) * 2048 + tn * 64) * 2;
    int nb0 = (t & 3) * 2;
    uint4 lo = { wv[0], wv[1], wv[2], wv[3] };
    uint4 hi = { wv[4], wv[5], wv[6], wv[7] };
    *(uint4*)(base + nb0 * 16) = lo;
    *(uint4*)(base + nb0 * 16 + 16) = hi;
}

// ---- multiplicity matrix A^T[src][dst] u8, packed-byte atomics ----
__global__ void histA(const int* __restrict__ es, const int* __restrict__ ed,
                      uint* __restrict__ A32, int E) {
    int i = blockIdx.x * 256 + threadIdx.x;
    if (i < E) {
        uint idx = (uint)es[i] * 2048u + (uint)ed[i];
        atomicAdd(&A32[idx >> 2], 1u << ((idx & 3) * 8));
    }
}

// ---- dense masked attention, src-quarter partials ----
// Block = 64 dst x 1 head x 512 src (quarter), 256 threads = 4 waves.
// grid 1024 -> 4 blocks/CU (LDS 40KB exactly). Swapped MFMAs; S redistributed
// C/D->B-frag layout fully in-register (16 shfl + cndmask), no S LDS.
__global__ void __launch_bounds__(256, 4) attn_kernel(
    const float* __restrict__ q, const ushort* __restrict__ kc, const ushort* __restrict__ vt,
    const uchar* __restrict__ A8, float* __restrict__ po, float* __restrict__ pz) {
    __shared__ __align__(16) char LK[2][8192];   // [buf][64 src x 128B]
    __shared__ __align__(16) char LV[2][8192];   // [buf][64 dim x 128B]
    __shared__ __align__(16) char LA[2][4096];   // [buf][64 src x 64 dst]

    int b = blockIdx.x;
    int sq = b >> 8, bh = b & 255;
    int h = bh & 7, dst0 = (bh >> 3) * 64;
    int t = threadIdx.x, w = t >> 6, l = t & 63, c = l & 15, g = l >> 4;

    const char* kH = (const char*)kc + (size_t)h * 262144;
    const char* vH = (const char*)vt + (size_t)h * 262144;

    // Q fragments: lane (c,g) holds Q[dst=dst0+w*16+c][dim=ch*32+8g..+7]
    h8 qf[2];
    {
        const float* qp = q + (size_t)(dst0 + w * 16 + c) * 512 + h * 64 + g * 8;
#pragma unroll
        for (int ch = 0; ch < 2; ++ch) {
            float4 f0 = *(const float4*)(qp + ch * 32);
            float4 f1 = *(const float4*)(qp + ch * 32 + 4);
            union { uint u[4]; h8 v; } U;
            U.u[0] = pk2(f0.x, f0.y); U.u[1] = pk2(f0.z, f0.w);
            U.u[2] = pk2(f1.x, f1.y); U.u[3] = pk2(f1.z, f1.w);
            qf[ch] = U.v;
        }
    }

    f4 of[4];
#pragma unroll
    for (int i = 0; i < 4; ++i) of[i] = (f4){0.f, 0.f, 0.f, 0.f};
    float z = 0.f;

    int r0 = t >> 3, b0 = t & 7;     // K/V staging: rows r0, r0+32; 16B block b0
    int ar_ = t >> 2, as_ = t & 3;   // A staging
    int gts0 = sq * 8;               // first global 64-src tile
    uint4 kr[2], vr[2], ar;

    // prologue: stage tile gts0 into buf 0
#pragma unroll
    for (int j = 0; j < 2; ++j) {
        int row = r0 + j * 32;
        kr[j] = *(const uint4*)(kH + (size_t)(gts0 * 64 + row) * 128 + b0 * 16);
        vr[j] = *(const uint4*)(vH + (size_t)row * 4096 + gts0 * 128 + b0 * 16);
        *(uint4*)(LK[0] + row * 128 + b0 * 16) = kr[j];
        *(uint4*)(LV[0] + row * 128 + b0 * 16) = vr[j];
    }
    ar = *(const uint4*)(A8 + (size_t)(gts0 * 64 + ar_) * 2048 + dst0 + as_ * 16);
    *(uint4*)(LA[0] + ar_ * 64 + as_ * 16) = ar;
    __syncthreads();

    int sl = c + 32 * (g & 1);       // shfl source lane (j=0,1); +16 for j=2,3
    bool hi = (g >> 1) != 0;

    for (int it = 0; it < 8; ++it) {
        int cur = it & 1;
        int gts = gts0 + it;
        // issue next-tile loads early
        if (it < 7) {
#pragma unroll
            for (int j = 0; j < 2; ++j) {
                int row = r0 + j * 32;
                kr[j] = *(const uint4*)(kH + (size_t)((gts + 1) * 64 + row) * 128 + b0 * 16);
                vr[j] = *(const uint4*)(vH + (size_t)row * 4096 + (gts + 1) * 128 + b0 * 16);
            }
            ar = *(const uint4*)(A8 + (size_t)((gts + 1) * 64 + ar_) * 2048 + dst0 + as_ * 16);
        }

        // QK^T swapped: sacc[nt] lane (c,g) = S[src=16nt+4g+r][dst=c]
        f4 sacc[4];
#pragma unroll
        for (int i = 0; i < 4; ++i) sacc[i] = (f4){0.f, 0.f, 0.f, 0.f};
#pragma unroll
        for (int nt = 0; nt < 4; ++nt)
#pragma unroll
            for (int ch = 0; ch < 2; ++ch) {
                h8 kf = *(const h8*)(LK[cur] + (nt * 16 + c) * 128 + (ch * 4 + g) * 16);
                sacc[nt] = __builtin_amdgcn_mfma_f32_16x16x32_f16(kf, qf[ch], sacc[nt], 0, 0, 0);
            }

        // exp + multiplicity mask + z; pack to fp16 pair words pw[nt][jj]
        uint pw[4][2];
        {
            const uchar* Ac = (const uchar*)LA[cur];
#pragma unroll
            for (int nt = 0; nt < 4; ++nt) {
                float e[4];
#pragma unroll
                for (int r = 0; r < 4; ++r) {
                    float sc = fminf(fmaxf(sacc[nt][r], -CLAMP2), CLAMP2);
                    float m = (float)Ac[(nt * 16 + 4 * g + r) * 64 + w * 16 + c];
                    e[r] = exp2f(sc) * m;
                    z += e[r];
                }
                pw[nt][0] = pk2(e[0], e[1]);
                pw[nt][1] = pk2(e[2], e[3]);
            }
        }

        // in-register redistribution to B-frag: sf[ch] word j <- lane sl+16*(j>>1),
        // pw[2ch + (g>>1)][j&1]
        h8 sf[2];
#pragma unroll
        for (int ch = 0; ch < 2; ++ch) {
            uint a0 = __shfl(pw[2 * ch][0], sl),      b0_ = __shfl(pw[2 * ch + 1][0], sl);
            uint a1 = __shfl(pw[2 * ch][1], sl),      b1_ = __shfl(pw[2 * ch + 1][1], sl);
            uint a2 = __shfl(pw[2 * ch][0], sl + 16), b2_ = __shfl(pw[2 * ch + 1][0], sl + 16);
            uint a3 = __shfl(pw[2 * ch][1], sl + 16), b3_ = __shfl(pw[2 * ch + 1][1], sl + 16);
            union { uint u[4]; h8 v; } S;
            S.u[0] = hi ? b0_ : a0;
            S.u[1] = hi ? b1_ : a1;
            S.u[2] = hi ? b2_ : a2;
            S.u[3] = hi ? b3_ : a3;
            sf[ch] = S.v;
        }

        // PV swapped: of[nt] lane (c,g) = O[dst=c][dim=16nt+4g+r]
#pragma unroll
        for (int nt = 0; nt < 4; ++nt)
#pragma unroll
            for (int ch = 0; ch < 2; ++ch) {
                h8 vf = *(const h8*)(LV[cur] + (nt * 16 + c) * 128 + (ch * 4 + g) * 16);
                of[nt] = __builtin_amdgcn_mfma_f32_16x16x32_f16(vf, sf[ch], of[nt], 0, 0, 0);
            }

        // write next tile into the other buffer
        if (it < 7) {
            int nb = cur ^ 1;
#pragma unroll
            for (int j = 0; j < 2; ++j) {
                int row = r0 + j * 32;
                *(uint4*)(LK[nb] + row * 128 + b0 * 16) = kr[j];
                *(uint4*)(LV[nb] + row * 128 + b0 * 16) = vr[j];
            }
            *(uint4*)(LA[nb] + ar_ * 64 + as_ * 16) = ar;
        }
        __syncthreads();
    }

    // z: reduce over g-groups (each dst column)
    z += __shfl_xor(z, 16);
    z += __shfl_xor(z, 32);

    // store partials
#pragma unroll
    for (int nt = 0; nt < 4; ++nt) {
        float4 o4 = { of[nt][0], of[nt][1], of[nt][2], of[nt][3] };
        *(float4*)&po[(size_t)b * 4096 + (w * 16 + c) * 64 + nt * 16 + 4 * g] = o4;
    }
    if (l < 16) pz[(size_t)b * 64 + w * 16 + c] = z;
}

// ---- combine 4 src-quarter partials, normalize, store ----
__global__ void combine_kernel(const float* __restrict__ po, const float* __restrict__ pz,
                               float* __restrict__ out) {
    int cb = blockIdx.x;           // 0..255 = (dt<<3)|h
    int h = cb & 7, dt = cb >> 3;
    int t = threadIdx.x, dl = t >> 2, dq = (t & 3) * 16;
    float4 acc[4] = {{0.f,0.f,0.f,0.f},{0.f,0.f,0.f,0.f},{0.f,0.f,0.f,0.f},{0.f,0.f,0.f,0.f}};
    float zs = 0.f;
#pragma unroll
    for (int sq = 0; sq < 4; ++sq) {
        const float4* P = (const float4*)(po + (size_t)(sq * 256 + cb) * 4096 + dl * 64 + dq);
#pragma unroll
        for (int i = 0; i < 4; ++i) {
            float4 x = P[i];
            acc[i].x += x.x; acc[i].y += x.y; acc[i].z += x.z; acc[i].w += x.w;
        }
        zs += pz[(size_t)(sq * 256 + cb) * 64 + dl];
    }
    float inv = 1.0f / zs;
    float4* O = (float4*)(out + (size_t)(dt * 64 + dl) * 512 + h * 64 + dq);
#pragma unroll
    for (int i = 0; i < 4; ++i) {
        float4 x = acc[i];
        x.x *= inv; x.y *= inv; x.z *= inv; x.w *= inv;
        O[i] = x;
    }
}

// ---------------- launch ----------------

extern "C" void kernel_launch(void* const* d_in, const int* in_sizes, int n_in,
                              void* d_out, int out_size, void* d_ws, size_t ws_size,
                              hipStream_t stream) {
    const float* q = (const float*)d_in[0];
    const float* k = (const float*)d_in[1];
    const float* v = (const float*)d_in[2];
    const int* esrc = (const int*)d_in[3];
    const int* edst = (const int*)d_in[4];
    float* out = (float*)d_out;
    const int E = in_sizes[3];

    uchar* A8 = (uchar*)d_ws;                               // 4MB  A^T[src][dst]
    ushort* kc = (ushort*)(A8 + (size_t)NNODES * NNODES);   // 2MB  fp16 [h][node][dim]
    ushort* vt = kc + (size_t)NHEAD * NNODES * DKDIM;       // 2MB  fp16 [h][dim][node]
    float* po = (float*)(vt + (size_t)NHEAD * NNODES * DKDIM);  // 16MB partial O
    float* pz = po + (size_t)1024 * 4096;                       // 256KB partial z

    conv_k<<<512, 256, 0, stream>>>(k, (uint4*)kc, (uint4*)A8);
    conv_vT<<<256, 256, 0, stream>>>(v, vt);
    histA<<<(E + 255) / 256, 256, 0, stream>>>(esrc, edst, (uint*)A8, E);
    attn_kernel<<<1024, 256, 0, stream>>>(q, kc, vt, A8, po, pz);
    combine_kernel<<<256, 256, 0, stream>>>(po, pz, out);
}

// Round 12
// 64.657 us; speedup vs baseline: 1.1786x; 1.1786x over previous
//
#include <hip/hip_runtime.h>

#define NNODES 2048
#define NHEAD 8
#define DKDIM 64

typedef unsigned int uint;
typedef unsigned short ushort;
typedef unsigned char uchar;
typedef __fp16 h2 __attribute__((ext_vector_type(2)));
typedef __fp16 h8 __attribute__((ext_vector_type(8)));
typedef float f4 __attribute__((ext_vector_type(4)));

#define KSCALE 0.18033688011112042f   // 0.125 * log2(e)
#define CLAMP2 14.426950408889634f    // 10 * log2(e)

__device__ __forceinline__ uint pk2(float a, float b) {
    union { h2 h; uint u; } x; x.h = __builtin_amdgcn_cvt_pkrtz(a, b); return x.u;
}

// ---- prep1: k -> fp16 [head][node][dim] (pre-scaled) + zero A ----
__global__ void prep1(const float* __restrict__ k, uint4* __restrict__ kc,
                      uint4* __restrict__ A4) {
    int i = blockIdx.x * 256 + threadIdx.x;      // 0..131071
    int dim8 = i & 7, node = (i >> 3) & 2047, h = i >> 14;
    const float* src = k + (size_t)node * 512 + h * 64 + dim8 * 8;
    float4 f0 = *(const float4*)src;
    float4 f1 = *(const float4*)(src + 4);
    uint4 o;
    o.x = pk2(f0.x * KSCALE, f0.y * KSCALE);
    o.y = pk2(f0.z * KSCALE, f0.w * KSCALE);
    o.z = pk2(f1.x * KSCALE, f1.y * KSCALE);
    o.w = pk2(f1.z * KSCALE, f1.w * KSCALE);
    kc[(h * 2048 + node) * 8 + dim8] = o;
    uint4 zz = {0u, 0u, 0u, 0u};
    A4[i] = zz;
    A4[i + 131072] = zz;
}

// ---- prep2: blocks 0..255 = v -> fp16 transposed [head][dim][node];
//             blocks 256..2303 = histA into A[dst][src] (packed-byte atomics) ----
__global__ void prep2(const float* __restrict__ v, ushort* __restrict__ vt,
                      const int* __restrict__ es, const int* __restrict__ ed,
                      uint* __restrict__ A32, int E) {
    __shared__ float tile[64][65];
    int b = blockIdx.x;
    int t = threadIdx.x;
    if (b < 256) {
        int h = b & 7, tn = b >> 3;
        int nl = t >> 2, dq = (t & 3) * 16;
        const float* src = v + ((size_t)(tn * 64 + nl)) * 512 + h * 64 + dq;
#pragma unroll
        for (int i = 0; i < 4; ++i) {
            float4 f = *(const float4*)(src + i * 4);
            tile[nl][dq + i * 4 + 0] = f.x;
            tile[nl][dq + i * 4 + 1] = f.y;
            tile[nl][dq + i * 4 + 2] = f.z;
            tile[nl][dq + i * 4 + 3] = f.w;
        }
        __syncthreads();
        int dim = t >> 2, nq = (t & 3) * 16;
        uint wv[8];
#pragma unroll
        for (int i = 0; i < 8; ++i)
            wv[i] = pk2(tile[nq + 2 * i][dim], tile[nq + 2 * i + 1][dim]);
        char* base = (char*)vt + ((size_t)(b & 7) * 64 + dim) * 4096 + (b >> 3) * 128;
        int nb0 = (t & 3) * 2;
        uint4 lo = { wv[0], wv[1], wv[2], wv[3] };
        uint4 hi = { wv[4], wv[5], wv[6], wv[7] };
        *(uint4*)(base + nb0 * 16) = lo;
        *(uint4*)(base + nb0 * 16 + 16) = hi;
    } else {
        int i = (b - 256) * 256 + t;
        if (i < E) {
            uint idx = (uint)ed[i] * 2048u + (uint)es[i];   // [dst][src]
            atomicAdd(&A32[idx >> 2], 1u << ((idx & 3) * 8));
        }
    }
}

// ---- dense masked attention ----
// Block = 64 dst x 1 head, 512 threads = 8 waves; half = w>>2 owns src half,
// wq = w&3 owns 16-dst strip. Swapped MFMAs; K/V LDS XOR-swizzled (T2);
// A [dst][src] staged to 80B-padded rows, one u32/nt; S redistributed
// C/D -> B-frag fully in-register (verified R11). In-block half combine.
__global__ void __launch_bounds__(512, 1) attn_kernel(
    const float* __restrict__ q, const ushort* __restrict__ kc, const ushort* __restrict__ vt,
    const uchar* __restrict__ A8, float* __restrict__ out) {
    __shared__ __align__(16) char LK[2][2][8192];   // [half][buf][64 src x 128B] swz
    __shared__ __align__(16) char LV[2][2][8192];   // [half][buf][64 dim x 128B] swz
    __shared__ __align__(16) char LA[2][2][5120];   // [half][buf][64 dst x 80B]

    int b = blockIdx.x;
    int h = b & 7;
    int dst0 = (b >> 3) * 64;
    int t = threadIdx.x;
    int w = t >> 6, half = w >> 2, wq = w & 3;
    int l = t & 63, c = l & 15, g = l >> 4;
    int ht = t & 255;

    const char* kH = (const char*)kc + (size_t)h * 262144;
    const char* vH = (const char*)vt + (size_t)h * 262144;

    // Q fragments: lane (c,g) holds Q[dst=dst0+wq*16+c][dim=ch*32+8g..+7]
    h8 qf[2];
    {
        const float* qp = q + (size_t)(dst0 + wq * 16 + c) * 512 + h * 64 + g * 8;
#pragma unroll
        for (int ch = 0; ch < 2; ++ch) {
            float4 f0 = *(const float4*)(qp + ch * 32);
            float4 f1 = *(const float4*)(qp + ch * 32 + 4);
            union { uint u[4]; h8 v; } U;
            U.u[0] = pk2(f0.x, f0.y); U.u[1] = pk2(f0.z, f0.w);
            U.u[2] = pk2(f1.x, f1.y); U.u[3] = pk2(f1.z, f1.w);
            qf[ch] = U.v;
        }
    }

    f4 of[4];
#pragma unroll
    for (int i = 0; i < 4; ++i) of[i] = (f4){0.f, 0.f, 0.f, 0.f};
    float z = 0.f;

    int r0 = ht >> 3, b0 = ht & 7;     // K/V staging: rows r0, r0+32; 16B block b0
    int ar_ = ht >> 2, as_ = ht & 3;   // A staging: dst row, 16B seg
    int ts0 = half * 16;
    uint4 kr[2], vr[2], ar;

    // prologue: stage tile ts0 into buf 0 (LDS swizzled: blk ^= row&7)
#pragma unroll
    for (int j = 0; j < 2; ++j) {
        int row = r0 + j * 32;
        kr[j] = *(const uint4*)(kH + (size_t)(ts0 * 64 + row) * 128 + b0 * 16);
        vr[j] = *(const uint4*)(vH + (size_t)row * 4096 + ts0 * 128 + b0 * 16);
        *(uint4*)(LK[half][0] + row * 128 + (b0 ^ (row & 7)) * 16) = kr[j];
        *(uint4*)(LV[half][0] + row * 128 + (b0 ^ (row & 7)) * 16) = vr[j];
    }
    ar = *(const uint4*)(A8 + (size_t)(dst0 + ar_) * 2048 + ts0 * 64 + as_ * 16);
    *(uint4*)(LA[half][0] + ar_ * 80 + as_ * 16) = ar;
    __syncthreads();

    int sl = c + 32 * (g & 1);       // shfl source lane (words 0,1); +16 for 2,3
    bool hi = (g >> 1) != 0;

    for (int it = 0; it < 16; ++it) {
        int cur = it & 1;
        int ts = ts0 + it;
        // issue next-tile global loads early (T14: issue-early / write-late)
        if (it < 15) {
#pragma unroll
            for (int j = 0; j < 2; ++j) {
                int row = r0 + j * 32;
                kr[j] = *(const uint4*)(kH + (size_t)((ts + 1) * 64 + row) * 128 + b0 * 16);
                vr[j] = *(const uint4*)(vH + (size_t)row * 4096 + (ts + 1) * 128 + b0 * 16);
            }
            ar = *(const uint4*)(A8 + (size_t)(dst0 + ar_) * 2048 + (ts + 1) * 64 + as_ * 16);
        }

        // QK^T swapped: sacc[nt] lane (c,g) = S[src=16nt+4g+r][dst=c]
        f4 sacc[4];
#pragma unroll
        for (int i = 0; i < 4; ++i) sacc[i] = (f4){0.f, 0.f, 0.f, 0.f};
        __builtin_amdgcn_s_setprio(1);
#pragma unroll
        for (int nt = 0; nt < 4; ++nt)
#pragma unroll
            for (int ch = 0; ch < 2; ++ch) {
                h8 kf = *(const h8*)(LK[half][cur] + (nt * 16 + c) * 128 +
                                     (((ch * 4 + g) ^ (c & 7)) * 16));
                sacc[nt] = __builtin_amdgcn_mfma_f32_16x16x32_f16(kf, qf[ch], sacc[nt], 0, 0, 0);
            }
        __builtin_amdgcn_s_setprio(0);

        // exp + multiplicity mask (one u32 per nt) + z; pack fp16 pair words
        uint pw[4][2];
#pragma unroll
        for (int nt = 0; nt < 4; ++nt) {
            uint aw = *(const uint*)(LA[half][cur] + (wq * 16 + c) * 80 + nt * 16 + 4 * g);
            float e[4];
#pragma unroll
            for (int r = 0; r < 4; ++r) {
                float sc = fminf(fmaxf(sacc[nt][r], -CLAMP2), CLAMP2);
                e[r] = exp2f(sc) * (float)((aw >> (8 * r)) & 255u);
                z += e[r];
            }
            pw[nt][0] = pk2(e[0], e[1]);
            pw[nt][1] = pk2(e[2], e[3]);
        }

        // in-register redistribution C/D -> B-frag (verified R11)
        h8 sf[2];
#pragma unroll
        for (int ch = 0; ch < 2; ++ch) {
            uint a0 = __shfl(pw[2 * ch][0], sl),      b0_ = __shfl(pw[2 * ch + 1][0], sl);
            uint a1 = __shfl(pw[2 * ch][1], sl),      b1_ = __shfl(pw[2 * ch + 1][1], sl);
            uint a2 = __shfl(pw[2 * ch][0], sl + 16), b2_ = __shfl(pw[2 * ch + 1][0], sl + 16);
            uint a3 = __shfl(pw[2 * ch][1], sl + 16), b3_ = __shfl(pw[2 * ch + 1][1], sl + 16);
            union { uint u[4]; h8 v; } S;
            S.u[0] = hi ? b0_ : a0;
            S.u[1] = hi ? b1_ : a1;
            S.u[2] = hi ? b2_ : a2;
            S.u[3] = hi ? b3_ : a3;
            sf[ch] = S.v;
        }

        // PV swapped: of[nt] lane (c,g) = O[dst=c][dim=16nt+4g+r]
        __builtin_amdgcn_s_setprio(1);
#pragma unroll
        for (int nt = 0; nt < 4; ++nt)
#pragma unroll
            for (int ch = 0; ch < 2; ++ch) {
                h8 vf = *(const h8*)(LV[half][cur] + (nt * 16 + c) * 128 +
                                     (((ch * 4 + g) ^ (c & 7)) * 16));
                of[nt] = __builtin_amdgcn_mfma_f32_16x16x32_f16(vf, sf[ch], of[nt], 0, 0, 0);
            }
        __builtin_amdgcn_s_setprio(0);

        // write next tile into the other buffer (swizzled), then barrier
        if (it < 15) {
            int nb = cur ^ 1;
#pragma unroll
            for (int j = 0; j < 2; ++j) {
                int row = r0 + j * 32;
                *(uint4*)(LK[half][nb] + row * 128 + (b0 ^ (row & 7)) * 16) = kr[j];
                *(uint4*)(LV[half][nb] + row * 128 + (b0 ^ (row & 7)) * 16) = vr[j];
            }
            *(uint4*)(LA[half][nb] + ar_ * 80 + as_ * 16) = ar;
        }
        __syncthreads();
    }

    // z: reduce over g-groups (each dst column)
    z += __shfl_xor(z, 16);
    z += __shfl_xor(z, 32);

    // combine halves + normalize via LDS (reuse LK/LV space)
    float* CL = (float*)&LK[0][0][0];    // [64 rows][65] f32
    float* CLz = (float*)&LV[0][0][0];   // [64]
    if (half == 1) {
#pragma unroll
        for (int nt = 0; nt < 4; ++nt)
#pragma unroll
            for (int r = 0; r < 4; ++r)
                CL[(wq * 16 + c) * 65 + nt * 16 + 4 * g + r] = of[nt][r];
        if (l < 16) CLz[wq * 16 + c] = z;
    }
    __syncthreads();
    if (half == 0) {
        float zt = 1.0f / (z + CLz[wq * 16 + c]);
#pragma unroll
        for (int nt = 0; nt < 4; ++nt)
#pragma unroll
            for (int r = 0; r < 4; ++r) {
                int idx = (wq * 16 + c) * 65 + nt * 16 + 4 * g + r;
                CL[idx] = (of[nt][r] + CL[idx]) * zt;
            }
    }
    __syncthreads();
    // coalesced store: wave w writes rows w*8 .. w*8+7, lane = dim
#pragma unroll
    for (int j = 0; j < 8; ++j) {
        int i2 = w * 8 + j;
        out[(size_t)(dst0 + i2) * 512 + h * 64 + l] = CL[i2 * 65 + l];
    }
}

// ---------------- launch ----------------

extern "C" void kernel_launch(void* const* d_in, const int* in_sizes, int n_in,
                              void* d_out, int out_size, void* d_ws, size_t ws_size,
                              hipStream_t stream) {
    const float* q = (const float*)d_in[0];
    const float* k = (const float*)d_in[1];
    const float* v = (const float*)d_in[2];
    const int* esrc = (const int*)d_in[3];
    const int* edst = (const int*)d_in[4];
    float* out = (float*)d_out;
    const int E = in_sizes[3];

    uchar* A8 = (uchar*)d_ws;                               // 4MB  A[dst][src]
    ushort* kc = (ushort*)(A8 + (size_t)NNODES * NNODES);   // 2MB  fp16 [h][node][dim]
    ushort* vt = kc + (size_t)NHEAD * NNODES * DKDIM;       // 2MB  fp16 [h][dim][node]

    prep1<<<512, 256, 0, stream>>>(k, (uint4*)kc, (uint4*)A8);
    prep2<<<2304, 256, 0, stream>>>(v, vt, esrc, edst, (uint*)A8, E);
    attn_kernel<<<256, 512, 0, stream>>>(q, kc, vt, A8, out);
}

// Round 13
// 63.580 us; speedup vs baseline: 1.1986x; 1.0169x over previous
//
#include <hip/hip_runtime.h>

#define NNODES 2048
#define NHEAD 8
#define DKDIM 64

typedef unsigned int uint;
typedef unsigned short ushort;
typedef unsigned char uchar;
typedef __fp16 h2 __attribute__((ext_vector_type(2)));
typedef __fp16 h8 __attribute__((ext_vector_type(8)));
typedef float f16v __attribute__((ext_vector_type(16)));

#define KSCALE 0.18033688011112042f   // 0.125 * log2(e)
#define CLAMP2 14.426950408889634f    // 10 * log2(e)

__device__ __forceinline__ uint pk2(float a, float b) {
    union { h2 h; uint u; } x; x.h = __builtin_amdgcn_cvt_pkrtz(a, b); return x.u;
}

// ---- prep1: k -> fp16 [head][node][dim] (pre-scaled) + zero A ----
__global__ void prep1(const float* __restrict__ k, uint4* __restrict__ kc,
                      uint4* __restrict__ A4) {
    int i = blockIdx.x * 256 + threadIdx.x;      // 0..131071
    int dim8 = i & 7, node = (i >> 3) & 2047, h = i >> 14;
    const float* src = k + (size_t)node * 512 + h * 64 + dim8 * 8;
    float4 f0 = *(const float4*)src;
    float4 f1 = *(const float4*)(src + 4);
    uint4 o;
    o.x = pk2(f0.x * KSCALE, f0.y * KSCALE);
    o.y = pk2(f0.z * KSCALE, f0.w * KSCALE);
    o.z = pk2(f1.x * KSCALE, f1.y * KSCALE);
    o.w = pk2(f1.z * KSCALE, f1.w * KSCALE);
    kc[(h * 2048 + node) * 8 + dim8] = o;
    uint4 zz = {0u, 0u, 0u, 0u};
    A4[i] = zz;
    A4[i + 131072] = zz;
}

// ---- prep2: blocks 0..255 = v -> fp16 transposed [head][dim][node];
//             blocks 256..2303 = histA into A[dst][src] (packed-byte atomics) ----
__global__ void prep2(const float* __restrict__ v, ushort* __restrict__ vt,
                      const int* __restrict__ es, const int* __restrict__ ed,
                      uint* __restrict__ A32, int E) {
    __shared__ float tile[64][65];
    int b = blockIdx.x;
    int t = threadIdx.x;
    if (b < 256) {
        int h = b & 7, tn = b >> 3;
        int nl = t >> 2, dq = (t & 3) * 16;
        const float* src = v + ((size_t)(tn * 64 + nl)) * 512 + h * 64 + dq;
#pragma unroll
        for (int i = 0; i < 4; ++i) {
            float4 f = *(const float4*)(src + i * 4);
            tile[nl][dq + i * 4 + 0] = f.x;
            tile[nl][dq + i * 4 + 1] = f.y;
            tile[nl][dq + i * 4 + 2] = f.z;
            tile[nl][dq + i * 4 + 3] = f.w;
        }
        __syncthreads();
        int dim = t >> 2, nq = (t & 3) * 16;
        uint wv[8];
#pragma unroll
        for (int i = 0; i < 8; ++i)
            wv[i] = pk2(tile[nq + 2 * i][dim], tile[nq + 2 * i + 1][dim]);
        char* base = (char*)vt + ((size_t)(b & 7) * 64 + dim) * 4096 + (b >> 3) * 128;
        int nb0 = (t & 3) * 2;
        uint4 lo = { wv[0], wv[1], wv[2], wv[3] };
        uint4 hi = { wv[4], wv[5], wv[6], wv[7] };
        *(uint4*)(base + nb0 * 16) = lo;
        *(uint4*)(base + nb0 * 16 + 16) = hi;
    } else {
        int i = (b - 256) * 256 + t;
        if (i < E) {
            uint idx = (uint)ed[i] * 2048u + (uint)es[i];   // [dst][src]
            atomicAdd(&A32[idx >> 2], 1u << ((idx & 3) * 8));
        }
    }
}

// ---- dense masked attention, 32x32x16 MFMA ----
// Block = 64 dst x 1 head, 512 threads = 8 waves. half = w>>2 owns 16 src
// tiles; wave (sr,dc) = quadrant 32src x 32dst. Swapped MFMAs:
// QK^T = mfma32(K, Q) -> D[src][dst]; PV = mfma32(V^T, S) x 2 dim-groups.
// S C/D -> B-frag via 8 shfl_xor(32) + lane-selects (32x32 C/D row =
// (reg&3)+8*(reg>>2)+4*hi: missing srcs live in lane l^32). K/V LDS
// XOR-swizzled; A[dst][src] in 80B-padded LDS rows. 4-phase end combine.
__global__ void __launch_bounds__(512, 1) attn_kernel(
    const float* __restrict__ q, const ushort* __restrict__ kc, const ushort* __restrict__ vt,
    const uchar* __restrict__ A8, float* __restrict__ out) {
    __shared__ __align__(16) char LK[2][2][8192];   // [half][buf][64 src x 128B] swz
    __shared__ __align__(16) char LV[2][2][8192];   // [half][buf][64 dim x 128B] swz
    __shared__ __align__(16) char LA[2][2][5120];   // [half][buf][64 dst x 80B]

    int b = blockIdx.x;
    int h = b & 7;
    int dst0 = (b >> 3) * 64;
    int t = threadIdx.x;
    int w = t >> 6, half = w >> 2;
    int u = w & 3, sr = u >> 1, dc = u & 1;
    int l = t & 63, lm = l & 31, hi = l >> 5;
    int ht = t & 255;

    const char* kH = (const char*)kc + (size_t)h * 262144;
    const char* vH = (const char*)vt + (size_t)h * 262144;

    // Q frags: qf[j] = Q[dst0+dc*32+lm][dim j*16 + hi*8 .. +7]
    h8 qf[4];
    {
        const float* qp = q + (size_t)(dst0 + dc * 32 + lm) * 512 + h * 64 + hi * 8;
#pragma unroll
        for (int j = 0; j < 4; ++j) {
            float4 f0 = *(const float4*)(qp + j * 16);
            float4 f1 = *(const float4*)(qp + j * 16 + 4);
            union { uint u4[4]; h8 v; } U;
            U.u4[0] = pk2(f0.x, f0.y); U.u4[1] = pk2(f0.z, f0.w);
            U.u4[2] = pk2(f1.x, f1.y); U.u4[3] = pk2(f1.z, f1.w);
            qf[j] = U.v;
        }
    }

    f16v of[2];
#pragma unroll
    for (int dg = 0; dg < 2; ++dg)
#pragma unroll
        for (int i = 0; i < 16; ++i) of[dg][i] = 0.f;
    float z = 0.f;

    int r0 = ht >> 3, b0 = ht & 7;     // K/V staging: rows r0, r0+32; block b0
    int ar_ = ht >> 2, as_ = ht & 3;   // A staging: dst row, 16B seg
    int ts0 = half * 16;
    uint4 kr[2], vr[2], ar;

    // prologue: stage tile ts0 into buf 0 (swz: blk ^= row&7)
#pragma unroll
    for (int j = 0; j < 2; ++j) {
        int row = r0 + j * 32;
        kr[j] = *(const uint4*)(kH + (size_t)(ts0 * 64 + row) * 128 + b0 * 16);
        vr[j] = *(const uint4*)(vH + (size_t)row * 4096 + ts0 * 128 + b0 * 16);
        *(uint4*)(LK[half][0] + row * 128 + (b0 ^ (row & 7)) * 16) = kr[j];
        *(uint4*)(LV[half][0] + row * 128 + (b0 ^ (row & 7)) * 16) = vr[j];
    }
    ar = *(const uint4*)(A8 + (size_t)(dst0 + ar_) * 2048 + ts0 * 64 + as_ * 16);
    *(uint4*)(LA[half][0] + ar_ * 80 + as_ * 16) = ar;
    __syncthreads();

    for (int it = 0; it < 16; ++it) {
        int cur = it & 1;
        int ts = ts0 + it;
        // issue next-tile global loads early
        if (it < 15) {
#pragma unroll
            for (int j = 0; j < 2; ++j) {
                int row = r0 + j * 32;
                kr[j] = *(const uint4*)(kH + (size_t)((ts + 1) * 64 + row) * 128 + b0 * 16);
                vr[j] = *(const uint4*)(vH + (size_t)row * 4096 + (ts + 1) * 128 + b0 * 16);
            }
            ar = *(const uint4*)(A8 + (size_t)(dst0 + ar_) * 2048 + (ts + 1) * 64 + as_ * 16);
        }

        // QK^T: sacc lane (dst=dc*32+lm, hi) reg -> src = sr*32+(reg&3)+8*(reg>>2)+4hi
        f16v sacc;
#pragma unroll
        for (int i = 0; i < 16; ++i) sacc[i] = 0.f;
        __builtin_amdgcn_s_setprio(1);
#pragma unroll
        for (int j = 0; j < 4; ++j) {
            h8 kf = *(const h8*)(LK[half][cur] + (sr * 32 + lm) * 128 +
                                 (((2 * j + hi) ^ (lm & 7)) * 16));
            sacc = __builtin_amdgcn_mfma_f32_32x32x16_f16(kf, qf[j], sacc, 0, 0, 0);
        }
        __builtin_amdgcn_s_setprio(0);

        // exp + multiplicity mask + z; pack fp16 pair words W[G][p]
        uint W[4][2];
        {
            const char* Ac = LA[half][cur];
#pragma unroll
            for (int G = 0; G < 4; ++G) {
                uint aw = *(const uint*)(Ac + (dc * 32 + lm) * 80 + sr * 32 + G * 8 + 4 * hi);
                float ee[4];
#pragma unroll
                for (int j2 = 0; j2 < 4; ++j2) {
                    float sc = fminf(fmaxf(sacc[4 * G + j2], -CLAMP2), CLAMP2);
                    ee[j2] = exp2f(sc) * (float)((aw >> (8 * j2)) & 255u);
                    z += ee[j2];
                }
                W[G][0] = pk2(ee[0], ee[1]);
                W[G][1] = pk2(ee[2], ee[3]);
            }
        }
        uint Wx[4][2];
#pragma unroll
        for (int G = 0; G < 4; ++G) {
            Wx[G][0] = __shfl_xor(W[G][0], 32);
            Wx[G][1] = __shfl_xor(W[G][1], 32);
        }

        // PV: B-frag for k-slice ks from own/other words; A = V^T frags
        __builtin_amdgcn_s_setprio(1);
#pragma unroll
        for (int ks = 0; ks < 2; ++ks) {
            union { uint u4[4]; h8 v; } S;
            S.u4[0] = hi ? Wx[2 * ks + 1][0] : W[2 * ks][0];
            S.u4[1] = hi ? Wx[2 * ks + 1][1] : W[2 * ks][1];
            S.u4[2] = hi ? W[2 * ks + 1][0] : Wx[2 * ks][0];
            S.u4[3] = hi ? W[2 * ks + 1][1] : Wx[2 * ks][1];
#pragma unroll
            for (int dg = 0; dg < 2; ++dg) {
                h8 vf = *(const h8*)(LV[half][cur] + (dg * 32 + lm) * 128 +
                                     (((sr * 4 + ks * 2 + hi) ^ (lm & 7)) * 16));
                of[dg] = __builtin_amdgcn_mfma_f32_32x32x16_f16(vf, S.v, of[dg], 0, 0, 0);
            }
        }
        __builtin_amdgcn_s_setprio(0);

        // write next tile into the other buffer (swizzled), then barrier
        if (it < 15) {
            int nb = cur ^ 1;
#pragma unroll
            for (int j = 0; j < 2; ++j) {
                int row = r0 + j * 32;
                *(uint4*)(LK[half][nb] + row * 128 + (b0 ^ (row & 7)) * 16) = kr[j];
                *(uint4*)(LV[half][nb] + row * 128 + (b0 ^ (row & 7)) * 16) = vr[j];
            }
            *(uint4*)(LA[half][nb] + ar_ * 80 + as_ * 16) = ar;
        }
        __syncthreads();
    }

    // z: lanes l and l^32 share dst col -> sum
    z += __shfl_xor(z, 32);

    // 4-phase combine into CL[64 dst][68] f32 (overlays LK), CLz in LV
    float* CL = (float*)&LK[0][0][0];
    float* CLz = (float*)&LV[0][0][0];
    int gid = half * 2 + sr;
    for (int p = 0; p < 4; ++p) {
        if (gid == p) {
#pragma unroll
            for (int dg = 0; dg < 2; ++dg)
#pragma unroll
                for (int reg = 0; reg < 16; ++reg) {
                    int dim = dg * 32 + (reg & 3) + 8 * (reg >> 2) + 4 * hi;
                    int idx = (dc * 32 + lm) * 68 + dim;
                    if (p == 0) CL[idx] = of[dg][reg];
                    else CL[idx] += of[dg][reg];
                }
            if (hi == 0) {
                if (p == 0) CLz[dc * 32 + lm] = z;
                else CLz[dc * 32 + lm] += z;
            }
        }
        __syncthreads();
    }

    // coalesced store: thread t -> dst row t>>3, dims (t&7)*8 .. +7
    {
        int dst = t >> 3, d8 = t & 7;
        float inv = 1.0f / CLz[dst];
        float4 o0 = *(float4*)(CL + dst * 68 + d8 * 8);
        float4 o1 = *(float4*)(CL + dst * 68 + d8 * 8 + 4);
        o0.x *= inv; o0.y *= inv; o0.z *= inv; o0.w *= inv;
        o1.x *= inv; o1.y *= inv; o1.z *= inv; o1.w *= inv;
        float* op = out + (size_t)(dst0 + dst) * 512 + h * 64 + d8 * 8;
        *(float4*)op = o0;
        *(float4*)(op + 4) = o1;
    }
}

// ---------------- launch ----------------

extern "C" void kernel_launch(void* const* d_in, const int* in_sizes, int n_in,
                              void* d_out, int out_size, void* d_ws, size_t ws_size,
                              hipStream_t stream) {
    const float* q = (const float*)d_in[0];
    const float* k = (const float*)d_in[1];
    const float* v = (const float*)d_in[2];
    const int* esrc = (const int*)d_in[3];
    const int* edst = (const int*)d_in[4];
    float* out = (float*)d_out;
    const int E = in_sizes[3];

    uchar* A8 = (uchar*)d_ws;                               // 4MB  A[dst][src]
    ushort* kc = (ushort*)(A8 + (size_t)NNODES * NNODES);   // 2MB  fp16 [h][node][dim]
    ushort* vt = kc + (size_t)NHEAD * NNODES * DKDIM;       // 2MB  fp16 [h][dim][node]

    prep1<<<512, 256, 0, stream>>>(k, (uint4*)kc, (uint4*)A8);
    prep2<<<2304, 256, 0, stream>>>(v, vt, esrc, edst, (uint*)A8, E);
    attn_kernel<<<256, 512, 0, stream>>>(q, kc, vt, A8, out);
}